// Round 1
// baseline (3042.251 us; speedup 1.0000x reference)
//
#include <hip/hip_runtime.h>
#include <hip/hip_bf16.h>
#include <cmath>

#define HH 128
#define WW 128
#define HWSZ (HH*WW)
#define BB 4
#define CC 64

// ---------------------------------------------------------------------------
// Kernel: transpose w_dcn (64,64,3,3) -> wT[ck][oc]  (ck = c*9+k, 576 x 64)
// ---------------------------------------------------------------------------
__global__ __launch_bounds__(256) void transpose_w_k(const float* __restrict__ w,
                                                     float* __restrict__ wT) {
    int idx = blockIdx.x * 256 + threadIdx.x;
    if (idx < 576 * 64) {
        int ck = idx >> 6, oc = idx & 63;
        wT[idx] = w[oc * 576 + ck];
    }
}

// ---------------------------------------------------------------------------
// Generic 3x3 SAME conv, 32x32 spatial tile, 2x2 px/thread, 8 oc/block.
// MODE 0: concat input (xfw|xcur|flow, IC=130) + lrelu
// MODE 1: plain input + lrelu
// MODE 2: plain input + offset/mask epilogue (conv3)
// ---------------------------------------------------------------------------
template<int IC, int MODE>
__global__ __launch_bounds__(256) void conv3x3_k(
    const float* __restrict__ in0, const float* __restrict__ in1,
    const float* __restrict__ in2, const float* __restrict__ wgt,
    const float* __restrict__ bias, float* __restrict__ outp,
    const float* __restrict__ flow, int OC)
{
    __shared__ __align__(16) float tS[4 * 1156];   // 4 ic x 34x34
    __shared__ __align__(16) float wS[8 * 4 * 12]; // 8 oc x 4 ic x 9(pad 12)

    const int tid = threadIdx.x;
    const int tx = tid & 15, ty = tid >> 4;
    const int x0 = blockIdx.x * 32, y0 = blockIdx.y * 32;
    const int ocg_count = OC >> 3;
    const int b  = blockIdx.z / ocg_count;
    const int o0 = (blockIdx.z % ocg_count) * 8;

    float acc[8][2][2] = {};

    for (int c0 = 0; c0 < IC; c0 += 4) {
        const int cn = (IC - c0) < 4 ? (IC - c0) : 4;
        // ---- stage input tile (34x34 per ic) ----
        for (int i = 0; i < cn; ++i) {
            const int ic = c0 + i;
            const float* src;
            int cidx;
            if (MODE == 0) {
                if (ic < 64)       { src = in0; cidx = b * 64 + ic; }
                else if (ic < 128) { src = in1; cidx = b * 64 + (ic - 64); }
                else               { src = in2; cidx = b * 2 + (ic - 128); }
            } else {
                src = in0; cidx = b * IC + ic;
            }
            const float* sp = src + (size_t)cidx * HWSZ;
            for (int li = tid; li < 1156; li += 256) {
                int row = li / 34, col = li - row * 34;
                int gy = y0 - 1 + row, gx = x0 - 1 + col;
                float v = 0.f;
                if ((unsigned)gy < (unsigned)HH && (unsigned)gx < (unsigned)WW)
                    v = sp[gy * WW + gx];
                tS[i * 1156 + li] = v;
            }
        }
        // ---- stage weights: 8 oc x cn ic x 9 ----
        for (int idx = tid; idx < 8 * 4 * 12; idx += 256) {
            int o = idx / 48, rem = idx - o * 48;
            int i = rem / 12, j = rem - i * 12;
            float v = 0.f;
            if (j < 9 && i < cn)
                v = wgt[((size_t)(o0 + o) * IC + (c0 + i)) * 9 + j];
            wS[idx] = v;
        }
        __syncthreads();

        #pragma unroll
        for (int i = 0; i < 4; ++i) {
            if (i >= cn) break;
            float r[4][4];
            const int base = i * 1156 + (2 * ty) * 34 + 2 * tx;
            #pragma unroll
            for (int a = 0; a < 4; ++a)
                #pragma unroll
                for (int c2 = 0; c2 < 4; ++c2)
                    r[a][c2] = tS[base + a * 34 + c2];
            #pragma unroll
            for (int o = 0; o < 8; ++o) {
                float wv[9];
                #pragma unroll
                for (int j = 0; j < 9; ++j) wv[j] = wS[(o * 4 + i) * 12 + j];
                #pragma unroll
                for (int a = 0; a < 2; ++a)
                    #pragma unroll
                    for (int c2 = 0; c2 < 2; ++c2) {
                        float s = 0.f;
                        #pragma unroll
                        for (int j = 0; j < 9; ++j)
                            s += wv[j] * r[a + j / 3][c2 + j % 3];
                        acc[o][a][c2] += s;
                    }
            }
        }
        __syncthreads();
    }

    // ---- epilogue ----
    #pragma unroll
    for (int o = 0; o < 8; ++o) {
        const int oc = o0 + o;
        const float bi = bias[oc];
        #pragma unroll
        for (int a = 0; a < 2; ++a)
            #pragma unroll
            for (int c2 = 0; c2 < 2; ++c2) {
                const int yy = y0 + 2 * ty + a, xx = x0 + 2 * tx + c2;
                float v = acc[o][a][c2] + bi;
                if (MODE == 2) {
                    float r;
                    if (oc < 288) {
                        float fl = flow[(((size_t)b * 2 + ((oc & 1) ? 0 : 1)) * HH + yy) * WW + xx];
                        r = 10.f * tanhf(v) + fl;
                    } else {
                        r = 1.f / (1.f + expf(-v));
                    }
                    outp[(((size_t)b * 432 + oc) * HH + yy) * WW + xx] = r;
                } else {
                    v = v >= 0.f ? v : 0.1f * v;
                    outp[(((size_t)b * OC + oc) * HH + yy) * WW + xx] = v;
                }
            }
    }
}

// ---------------------------------------------------------------------------
// Fused deformable conv: 16 pixels (one row segment) per block.
// Phase 1: 16 px x 144 (dg,k) bilinear samples -> LDS samp[576][16]
// Phase 2: einsum over (c,k) with transposed weights wT[ck][oc]
// ---------------------------------------------------------------------------
__global__ __launch_bounds__(256) void deform_k(
    const float* __restrict__ xin, const float* __restrict__ offm,
    const float* __restrict__ wT, const float* __restrict__ bias,
    float* __restrict__ outp)
{
    __shared__ __align__(16) float samp[576 * 16]; // 36864 B

    const int tid = threadIdx.x;
    const int x0 = blockIdx.x * 16;
    const int y  = blockIdx.y;
    const int b  = blockIdx.z;
    const float* offb = offm + (size_t)b * 432 * HWSZ;
    const float* xb   = xin  + (size_t)b * 64  * HWSZ;

    for (int s = tid; s < 2304; s += 256) {
        const int p = s & 15, dgk = s >> 4;
        const int xp = x0 + p;
        const int pix = y * WW + xp;
        const float dy = offb[(size_t)(2 * dgk) * HWSZ + pix];
        const float dx = offb[(size_t)(2 * dgk + 1) * HWSZ + pix];
        const float mk = offb[(size_t)(288 + dgk) * HWSZ + pix];
        const int k = dgk % 9, dg = dgk / 9;
        const float py = dy + (float)(k / 3) - 1.f + (float)y;
        const float px = dx + (float)(k % 3) - 1.f + (float)xp;
        const float y0f = floorf(py), x0f = floorf(px);
        const float ly = py - y0f, lx = px - x0f;
        const int yi = (int)y0f, xi = (int)x0f;
        const float w00 = (1.f - ly) * (1.f - lx), w01 = (1.f - ly) * lx;
        const float w10 = ly * (1.f - lx),         w11 = ly * lx;
        const bool vy0 = (unsigned)yi < (unsigned)HH, vy1 = (unsigned)(yi + 1) < (unsigned)HH;
        const bool vx0 = (unsigned)xi < (unsigned)WW, vx1 = (unsigned)(xi + 1) < (unsigned)WW;
        const float f00 = (vy0 && vx0) ? w00 : 0.f;
        const float f01 = (vy0 && vx1) ? w01 : 0.f;
        const float f10 = (vy1 && vx0) ? w10 : 0.f;
        const float f11 = (vy1 && vx1) ? w11 : 0.f;
        const int cy0 = min(max(yi, 0), HH - 1), cy1 = min(max(yi + 1, 0), HH - 1);
        const int cx0 = min(max(xi, 0), WW - 1), cx1 = min(max(xi + 1, 0), WW - 1);
        const int i00 = cy0 * WW + cx0, i01 = cy0 * WW + cx1;
        const int i10 = cy1 * WW + cx0, i11 = cy1 * WW + cx1;
        const float* xc = xb + (size_t)(dg * 4) * HWSZ;
        #pragma unroll
        for (int cc = 0; cc < 4; ++cc) {
            float v = f00 * xc[i00] + f01 * xc[i01] + f10 * xc[i10] + f11 * xc[i11];
            samp[((dg * 4 + cc) * 9 + k) * 16 + p] = v * mk;
            xc += HWSZ;
        }
    }
    __syncthreads();

    const int u = tid & 15, p2 = tid >> 4;
    float a0 = 0.f, a1 = 0.f, a2 = 0.f, a3 = 0.f;
    const float4* wT4 = (const float4*)wT;
    #pragma unroll 4
    for (int ck = 0; ck < 576; ++ck) {
        const float s = samp[ck * 16 + p2];
        const float4 wv = wT4[ck * 16 + u];
        a0 += s * wv.x; a1 += s * wv.y; a2 += s * wv.z; a3 += s * wv.w;
    }
    const int oc = u * 4;
    const int xp = x0 + p2;
    size_t ob = (((size_t)b * 64 + oc) * HH + y) * WW + xp;
    outp[ob]            = a0 + bias[oc];
    outp[ob + HWSZ]     = a1 + bias[oc + 1];
    outp[ob + 2 * HWSZ] = a2 + bias[oc + 2];
    outp[ob + 3 * HWSZ] = a3 + bias[oc + 3];
}

// ---------------------------------------------------------------------------
extern "C" void kernel_launch(void* const* d_in, const int* in_sizes, int n_in,
                              void* d_out, int out_size, void* d_ws, size_t ws_size,
                              hipStream_t stream) {
    const float* x    = (const float*)d_in[0];
    const float* xfw  = (const float*)d_in[1];
    const float* xcur = (const float*)d_in[2];
    const float* flow = (const float*)d_in[3];
    const float* w0   = (const float*)d_in[4];
    const float* b0   = (const float*)d_in[5];
    const float* w1   = (const float*)d_in[6];
    const float* b1   = (const float*)d_in[7];
    const float* w2   = (const float*)d_in[8];
    const float* b2   = (const float*)d_in[9];
    const float* w3   = (const float*)d_in[10];
    const float* b3   = (const float*)d_in[11];
    const float* wdcn = (const float*)d_in[12];
    const float* bdcn = (const float*)d_in[13];
    float* out = (float*)d_out;
    float* ws  = (float*)d_ws;

    float* h0   = ws;
    float* h1   = h0 + (size_t)BB * CC * HWSZ;
    float* h2   = h1 + (size_t)BB * CC * HWSZ;
    float* offm = h2 + (size_t)BB * CC * HWSZ;
    float* wT   = offm + (size_t)BB * 432 * HWSZ;

    transpose_w_k<<<dim3(144), dim3(256), 0, stream>>>(wdcn, wT);
    conv3x3_k<130, 0><<<dim3(4, 4, BB * 8),  dim3(256), 0, stream>>>(xfw, xcur, flow, w0, b0, h0, nullptr, 64);
    conv3x3_k<64, 1><<<dim3(4, 4, BB * 8),   dim3(256), 0, stream>>>(h0, nullptr, nullptr, w1, b1, h1, nullptr, 64);
    conv3x3_k<64, 1><<<dim3(4, 4, BB * 8),   dim3(256), 0, stream>>>(h1, nullptr, nullptr, w2, b2, h2, nullptr, 64);
    conv3x3_k<64, 2><<<dim3(4, 4, BB * 54),  dim3(256), 0, stream>>>(h2, nullptr, nullptr, w3, b3, offm, flow, 432);
    deform_k<<<dim3(8, 128, BB), dim3(256), 0, stream>>>(x, offm, wT, bdcn, out);
}

// Round 2
// 1016.413 us; speedup vs baseline: 2.9931x; 2.9931x over previous
//
#include <hip/hip_runtime.h>
#include <hip/hip_bf16.h>
#include <cmath>

#define HH 128
#define WW 128
#define HWSZ (HH*WW)
#define BB 4
#define CC 64

typedef __attribute__((ext_vector_type(8))) short short8;
typedef __attribute__((ext_vector_type(16))) float f32x16;

__device__ __forceinline__ ushort bf16_rn(float f) {
    uint u = __builtin_bit_cast(uint, f);
    return (ushort)((u + 0x7fffu + ((u >> 16) & 1u)) >> 16);
}
__device__ __forceinline__ float bf16_f(ushort h) {
    uint u = ((uint)h) << 16;
    return __builtin_bit_cast(float, u);
}

// ---------------------------------------------------------------------------
// Weight prep: w fp32 [OC][K] -> whi/wlo bf16 [OCpad][KPAD], zero padded.
// ---------------------------------------------------------------------------
__global__ __launch_bounds__(256) void prep_w_k(const float* __restrict__ w,
                                                ushort* __restrict__ whi,
                                                ushort* __restrict__ wlo,
                                                int OC, int K, int OCpad, int KPAD) {
    int idx = blockIdx.x * 256 + threadIdx.x;
    if (idx >= OCpad * KPAD) return;
    int oc = idx / KPAD, k = idx - oc * KPAD;
    float v = (oc < OC && k < K) ? w[(size_t)oc * K + k] : 0.f;
    ushort h = bf16_rn(v);
    ushort l = bf16_rn(v - bf16_f(h));
    whi[idx] = h;
    wlo[idx] = l;
}

// ---------------------------------------------------------------------------
// transpose w_dcn (64,64,3,3) -> wT[ck][oc]  (for deform kernel)
// ---------------------------------------------------------------------------
__global__ __launch_bounds__(256) void transpose_w_k(const float* __restrict__ w,
                                                     float* __restrict__ wT) {
    int idx = blockIdx.x * 256 + threadIdx.x;
    if (idx < 576 * 64) {
        int ck = idx >> 6, oc = idx & 63;
        wT[idx] = w[oc * 576 + ck];
    }
}

// ---------------------------------------------------------------------------
// Implicit-GEMM MFMA conv3x3 (split bf16x2 for ~fp32 accuracy).
// Block: 64 oc x 128 px (one full image row). 4 waves in 2(M)x2(N) grid,
// each wave: 32 oc x 64 px via mfma_f32_32x32x16_bf16, K = IC*9 (padded /32).
// MODE 0: concat(xfw|xcur|flow) input, lrelu.  MODE 1: lrelu.
// MODE 2: conv3 epilogue (10*tanh + reversed flow | sigmoid), OC=432 masked.
// ---------------------------------------------------------------------------
template<int MODE, int IC, int KPAD>
__global__ __launch_bounds__(256) void mfma_conv_k(
    const float* __restrict__ in0, const float* __restrict__ in1,
    const float* __restrict__ in2,
    const ushort* __restrict__ whi, const ushort* __restrict__ wlo,
    const float* __restrict__ bias, float* __restrict__ outp,
    const float* __restrict__ flow)
{
    constexpr int NCHUNK = KPAD / 32;
    constexpr int LDK = 40;                      // padded k-stride (bf16 units)

    __shared__ ushort wHi[64 * LDK], wLo[64 * LDK];
    __shared__ ushort iHi[128 * LDK], iLo[128 * LDK];

    const int tid  = threadIdx.x;
    const int row  = blockIdx.x;                 // 0 .. B*H-1
    const int b    = row >> 7, y = row & 127;
    const int o0   = blockIdx.y * 64;

    const int wave = tid >> 6, lane = tid & 63;
    const int wm   = wave >> 1, wn = wave & 1;
    const int l31  = lane & 31, lhi = lane >> 5;

    const int spx  = tid & 127;                  // im2col px
    const int skh  = tid >> 7;                   // im2col k-half (16 k each)
    const int woc  = tid >> 2;                   // weight oc
    const int wq   = tid & 3;                    // weight k-quarter (8 k each)

    f32x16 acc[2] = {};

    for (int kc = 0; kc < NCHUNK; ++kc) {
        // ---- stage weights: 64 oc x 32 k (bf16 hi/lo, pre-split) ----
        {
            const size_t g = (size_t)(o0 + woc) * KPAD + kc * 32 + wq * 8;
            *(short8*)&wHi[woc * LDK + wq * 8] = *(const short8*)&whi[g];
            *(short8*)&wLo[woc * LDK + wq * 8] = *(const short8*)&wlo[g];
        }
        // ---- stage im2col: 32 k x 128 px, transposed to [px][k] ----
        {
            ushort vh[16], vl[16];
            #pragma unroll
            for (int j = 0; j < 16; ++j) {
                const int k  = kc * 32 + skh * 16 + j;   // wave-uniform
                const int ic = k / 9;
                const int kk = k - ic * 9;
                const int ky = kk / 3;
                const int kx = kk - ky * 3;
                const int gy = y + ky - 1;
                const int gx = spx + kx - 1;
                const float* p = nullptr;
                if (MODE == 0) {
                    if (ic < 64)       p = in0 + ((size_t)b * 64 + ic) * HWSZ;
                    else if (ic < 128) p = in1 + ((size_t)b * 64 + ic - 64) * HWSZ;
                    else if (ic < 130) p = in2 + ((size_t)b * 2  + ic - 128) * HWSZ;
                } else {
                    p = in0 + ((size_t)b * IC + ic) * HWSZ;
                }
                float v = 0.f;
                if (p && (unsigned)gy < (unsigned)HH && (unsigned)gx < (unsigned)WW)
                    v = p[gy * WW + gx];
                vh[j] = bf16_rn(v);
                vl[j] = bf16_rn(v - bf16_f(vh[j]));
            }
            #pragma unroll
            for (int jg = 0; jg < 2; ++jg) {
                short8 ph, pl;
                #pragma unroll
                for (int j2 = 0; j2 < 8; ++j2) {
                    ph[j2] = (short)vh[jg * 8 + j2];
                    pl[j2] = (short)vl[jg * 8 + j2];
                }
                *(short8*)&iHi[spx * LDK + skh * 16 + jg * 8] = ph;
                *(short8*)&iLo[spx * LDK + skh * 16 + jg * 8] = pl;
            }
        }
        __syncthreads();

        // ---- MFMA: 2 K-halves x 2 px-groups x 3 split terms ----
        #pragma unroll
        for (int ks = 0; ks < 2; ++ks) {
            const int koff = ks * 16 + lhi * 8;
            const short8 ah = *(const short8*)&wHi[(wm * 32 + l31) * LDK + koff];
            const short8 al = *(const short8*)&wLo[(wm * 32 + l31) * LDK + koff];
            #pragma unroll
            for (int pg = 0; pg < 2; ++pg) {
                const int ib = (wn * 64 + pg * 32 + l31) * LDK + koff;
                const short8 bh = *(const short8*)&iHi[ib];
                const short8 bl = *(const short8*)&iLo[ib];
                acc[pg] = __builtin_amdgcn_mfma_f32_32x32x16_bf16(ah, bh, acc[pg], 0, 0, 0);
                acc[pg] = __builtin_amdgcn_mfma_f32_32x32x16_bf16(ah, bl, acc[pg], 0, 0, 0);
                acc[pg] = __builtin_amdgcn_mfma_f32_32x32x16_bf16(al, bh, acc[pg], 0, 0, 0);
            }
        }
        __syncthreads();
    }

    // ---- epilogue ----
    #pragma unroll
    for (int pg = 0; pg < 2; ++pg) {
        const int px = wn * 64 + pg * 32 + l31;
        #pragma unroll
        for (int r = 0; r < 16; ++r) {
            const int ocl = wm * 32 + (r & 3) + 8 * (r >> 2) + 4 * lhi;
            const int oc  = o0 + ocl;
            float v = acc[pg][r];
            if (MODE == 2) {
                if (oc < 432) {
                    v += bias[oc];
                    float res;
                    if (oc < 288) {
                        const float fl = flow[(((size_t)b * 2 + ((oc & 1) ? 0 : 1)) * HH + y) * WW + px];
                        res = 10.f * tanhf(v) + fl;
                    } else {
                        res = 1.f / (1.f + expf(-v));
                    }
                    outp[(((size_t)b * 432 + oc) * HH + y) * WW + px] = res;
                }
            } else {
                v += bias[oc];
                v = v >= 0.f ? v : 0.1f * v;
                outp[(((size_t)b * 64 + oc) * HH + y) * WW + px] = v;
            }
        }
    }
}

// ---------------------------------------------------------------------------
// Fused deformable conv (unchanged from passing round).
// ---------------------------------------------------------------------------
__global__ __launch_bounds__(256) void deform_k(
    const float* __restrict__ xin, const float* __restrict__ offm,
    const float* __restrict__ wT, const float* __restrict__ bias,
    float* __restrict__ outp)
{
    __shared__ __align__(16) float samp[576 * 16]; // 36864 B

    const int tid = threadIdx.x;
    const int x0 = blockIdx.x * 16;
    const int y  = blockIdx.y;
    const int b  = blockIdx.z;
    const float* offb = offm + (size_t)b * 432 * HWSZ;
    const float* xb   = xin  + (size_t)b * 64  * HWSZ;

    for (int s = tid; s < 2304; s += 256) {
        const int p = s & 15, dgk = s >> 4;
        const int xp = x0 + p;
        const int pix = y * WW + xp;
        const float dy = offb[(size_t)(2 * dgk) * HWSZ + pix];
        const float dx = offb[(size_t)(2 * dgk + 1) * HWSZ + pix];
        const float mk = offb[(size_t)(288 + dgk) * HWSZ + pix];
        const int k = dgk % 9, dg = dgk / 9;
        const float py = dy + (float)(k / 3) - 1.f + (float)y;
        const float px = dx + (float)(k % 3) - 1.f + (float)xp;
        const float y0f = floorf(py), x0f = floorf(px);
        const float ly = py - y0f, lx = px - x0f;
        const int yi = (int)y0f, xi = (int)x0f;
        const float w00 = (1.f - ly) * (1.f - lx), w01 = (1.f - ly) * lx;
        const float w10 = ly * (1.f - lx),         w11 = ly * lx;
        const bool vy0 = (unsigned)yi < (unsigned)HH, vy1 = (unsigned)(yi + 1) < (unsigned)HH;
        const bool vx0 = (unsigned)xi < (unsigned)WW, vx1 = (unsigned)(xi + 1) < (unsigned)WW;
        const float f00 = (vy0 && vx0) ? w00 : 0.f;
        const float f01 = (vy0 && vx1) ? w01 : 0.f;
        const float f10 = (vy1 && vx0) ? w10 : 0.f;
        const float f11 = (vy1 && vx1) ? w11 : 0.f;
        const int cy0 = min(max(yi, 0), HH - 1), cy1 = min(max(yi + 1, 0), HH - 1);
        const int cx0 = min(max(xi, 0), WW - 1), cx1 = min(max(xi + 1, 0), WW - 1);
        const int i00 = cy0 * WW + cx0, i01 = cy0 * WW + cx1;
        const int i10 = cy1 * WW + cx0, i11 = cy1 * WW + cx1;
        const float* xc = xb + (size_t)(dg * 4) * HWSZ;
        #pragma unroll
        for (int cc = 0; cc < 4; ++cc) {
            float v = f00 * xc[i00] + f01 * xc[i01] + f10 * xc[i10] + f11 * xc[i11];
            samp[((dg * 4 + cc) * 9 + k) * 16 + p] = v * mk;
            xc += HWSZ;
        }
    }
    __syncthreads();

    const int u = tid & 15, p2 = tid >> 4;
    float a0 = 0.f, a1 = 0.f, a2 = 0.f, a3 = 0.f;
    const float4* wT4 = (const float4*)wT;
    #pragma unroll 4
    for (int ck = 0; ck < 576; ++ck) {
        const float s = samp[ck * 16 + p2];
        const float4 wv = wT4[ck * 16 + u];
        a0 += s * wv.x; a1 += s * wv.y; a2 += s * wv.z; a3 += s * wv.w;
    }
    const int oc = u * 4;
    const int xp = x0 + p2;
    size_t ob = (((size_t)b * 64 + oc) * HH + y) * WW + xp;
    outp[ob]            = a0 + bias[oc];
    outp[ob + HWSZ]     = a1 + bias[oc + 1];
    outp[ob + 2 * HWSZ] = a2 + bias[oc + 2];
    outp[ob + 3 * HWSZ] = a3 + bias[oc + 3];
}

// ---------------------------------------------------------------------------
extern "C" void kernel_launch(void* const* d_in, const int* in_sizes, int n_in,
                              void* d_out, int out_size, void* d_ws, size_t ws_size,
                              hipStream_t stream) {
    const float* x    = (const float*)d_in[0];
    const float* xfw  = (const float*)d_in[1];
    const float* xcur = (const float*)d_in[2];
    const float* flow = (const float*)d_in[3];
    const float* w0   = (const float*)d_in[4];
    const float* b0   = (const float*)d_in[5];
    const float* w1   = (const float*)d_in[6];
    const float* b1   = (const float*)d_in[7];
    const float* w2   = (const float*)d_in[8];
    const float* b2   = (const float*)d_in[9];
    const float* w3   = (const float*)d_in[10];
    const float* b3   = (const float*)d_in[11];
    const float* wdcn = (const float*)d_in[12];
    const float* bdcn = (const float*)d_in[13];
    float* out = (float*)d_out;
    float* ws  = (float*)d_ws;

    // workspace layout (floats)
    float* h0   = ws;                              // 4*64*16384
    float* h1   = h0 + (size_t)BB * CC * HWSZ;     // 4*64*16384
    float* offm = h1 + (size_t)BB * CC * HWSZ;     // 4*432*16384
    float* wT   = offm + (size_t)BB * 432 * HWSZ;  // 576*64
    ushort* wp  = (ushort*)(wT + 576 * 64);
    ushort* w0hi = wp;                 ushort* w0lo = w0hi + 64 * 1184;
    ushort* w1hi = w0lo + 64 * 1184;   ushort* w1lo = w1hi + 64 * 576;
    ushort* w2hi = w1lo + 64 * 576;    ushort* w2lo = w2hi + 64 * 576;
    ushort* w3hi = w2lo + 64 * 576;    ushort* w3lo = w3hi + 448 * 576;
    // conv2 output reuses h0 (h0 is dead after conv1 reads it)
    float* h2 = h0;

    prep_w_k<<<dim3((64 * 1184 + 255) / 256), dim3(256), 0, stream>>>(w0, w0hi, w0lo, 64, 1170, 64, 1184);
    prep_w_k<<<dim3((64 * 576 + 255) / 256),  dim3(256), 0, stream>>>(w1, w1hi, w1lo, 64, 576, 64, 576);
    prep_w_k<<<dim3((64 * 576 + 255) / 256),  dim3(256), 0, stream>>>(w2, w2hi, w2lo, 64, 576, 64, 576);
    prep_w_k<<<dim3((448 * 576 + 255) / 256), dim3(256), 0, stream>>>(w3, w3hi, w3lo, 432, 576, 448, 576);
    transpose_w_k<<<dim3(144), dim3(256), 0, stream>>>(wdcn, wT);

    mfma_conv_k<0, 130, 1184><<<dim3(BB * HH, 1), dim3(256), 0, stream>>>(xfw, xcur, flow, w0hi, w0lo, b0, h0, nullptr);
    mfma_conv_k<1, 64, 576><<<dim3(BB * HH, 1), dim3(256), 0, stream>>>(h0, nullptr, nullptr, w1hi, w1lo, b1, h1, nullptr);
    mfma_conv_k<1, 64, 576><<<dim3(BB * HH, 1), dim3(256), 0, stream>>>(h1, nullptr, nullptr, w2hi, w2lo, b2, h2, nullptr);
    mfma_conv_k<2, 64, 576><<<dim3(BB * HH, 7), dim3(256), 0, stream>>>(h2, nullptr, nullptr, w3hi, w3lo, b3, offm, flow);

    deform_k<<<dim3(8, 128, BB), dim3(256), 0, stream>>>(x, offm, wT, bdcn, out);
}

// Round 3
// 771.157 us; speedup vs baseline: 3.9450x; 1.3180x over previous
//
#include <hip/hip_runtime.h>
#include <hip/hip_bf16.h>
#include <cmath>

#define HH 128
#define WW 128
#define HWSZ (HH*WW)
#define BB 4
#define CC 64

typedef __attribute__((ext_vector_type(8))) short short8;
typedef __attribute__((ext_vector_type(4))) short sh4;
typedef __attribute__((ext_vector_type(16))) float f32x16;

__device__ __forceinline__ ushort bf16_rn(float f) {
    uint u = __builtin_bit_cast(uint, f);
    return (ushort)((u + 0x7fffu + ((u >> 16) & 1u)) >> 16);
}
__device__ __forceinline__ float bf16_f(ushort h) {
    uint u = ((uint)h) << 16;
    return __builtin_bit_cast(float, u);
}

// ---------------------------------------------------------------------------
// Weight prep: w fp32 [OC][K] -> whi/wlo bf16 [OCpad][KPAD], zero padded.
// ---------------------------------------------------------------------------
__global__ __launch_bounds__(256) void prep_w_k(const float* __restrict__ w,
                                                ushort* __restrict__ whi,
                                                ushort* __restrict__ wlo,
                                                int OC, int K, int OCpad, int KPAD) {
    int idx = blockIdx.x * 256 + threadIdx.x;
    if (idx >= OCpad * KPAD) return;
    int oc = idx / KPAD, k = idx - oc * KPAD;
    float v = (oc < OC && k < K) ? w[(size_t)oc * K + k] : 0.f;
    ushort h = bf16_rn(v);
    ushort l = bf16_rn(v - bf16_f(h));
    whi[idx] = h;
    wlo[idx] = l;
}

// ---------------------------------------------------------------------------
// Deform weight prep: wdcn [oc][c][k] -> k-major reorder [oc][kidx=k*64+c],
// split bf16 hi/lo.
// ---------------------------------------------------------------------------
__global__ __launch_bounds__(256) void prep_wd_k(const float* __restrict__ w,
                                                 ushort* __restrict__ whi,
                                                 ushort* __restrict__ wlo) {
    int idx = blockIdx.x * 256 + threadIdx.x;
    if (idx >= 64 * 576) return;
    int oc = idx / 576, kidx = idx - oc * 576;
    int k = kidx >> 6, c = kidx & 63;
    float v = w[(size_t)oc * 576 + c * 9 + k];
    ushort h = bf16_rn(v);
    ushort l = bf16_rn(v - bf16_f(h));
    whi[idx] = h;
    wlo[idx] = l;
}

// ---------------------------------------------------------------------------
// Implicit-GEMM MFMA conv3x3 (split bf16x2 for ~fp32 accuracy).
// Block: 64 oc x 128 px (one image row), 512 threads = 8 waves in 2(M)x4(N)
// grid, each wave one 32oc x 32px tile via mfma_f32_32x32x16_bf16.
// MODE 0: concat(xfw|xcur|flow) input, lrelu.  MODE 1: lrelu.
// MODE 2: conv3 epilogue (10*tanh + reversed flow | sigmoid), OC=432 masked.
// ---------------------------------------------------------------------------
template<int MODE, int IC, int KPAD>
__global__ __launch_bounds__(512) void mfma_conv_k(
    const float* __restrict__ in0, const float* __restrict__ in1,
    const float* __restrict__ in2,
    const ushort* __restrict__ whi, const ushort* __restrict__ wlo,
    const float* __restrict__ bias, float* __restrict__ outp,
    const float* __restrict__ flow)
{
    constexpr int NCHUNK = KPAD / 32;
    constexpr int LDK = 40;                      // padded k-stride (bf16 units)

    __shared__ ushort wHi[64 * LDK], wLo[64 * LDK];
    __shared__ ushort iHi[128 * LDK], iLo[128 * LDK];

    const int tid  = threadIdx.x;
    const int row  = blockIdx.x;                 // 0 .. B*H-1
    const int b    = row >> 7, y = row & 127;
    const int o0   = blockIdx.y * 64;

    const int wave = tid >> 6, lane = tid & 63;
    const int wm   = wave >> 2, wn = wave & 3;   // 2 x 4 wave grid
    const int l31  = lane & 31, lhi = lane >> 5;

    const int spx  = tid & 127;                  // im2col px
    const int sko  = tid >> 7;                   // im2col k-octet (8 k each)

    f32x16 acc = {};

    for (int kc = 0; kc < NCHUNK; ++kc) {
        // ---- stage weights: 64 oc x 32 k (first 4 waves) ----
        if (tid < 256) {
            const int woc = tid >> 2, wq = tid & 3;
            const size_t g = (size_t)(o0 + woc) * KPAD + kc * 32 + wq * 8;
            *(short8*)&wHi[woc * LDK + wq * 8] = *(const short8*)&whi[g];
            *(short8*)&wLo[woc * LDK + wq * 8] = *(const short8*)&wlo[g];
        }
        // ---- stage im2col: 32 k x 128 px, transposed to [px][k] ----
        {
            ushort vh[8], vl[8];
            #pragma unroll
            for (int j = 0; j < 8; ++j) {
                const int k  = kc * 32 + sko * 8 + j;    // wave-uniform
                const int ic = k / 9;
                const int kk = k - ic * 9;
                const int ky = kk / 3;
                const int kx = kk - ky * 3;
                const int gy = y + ky - 1;
                const int gx = spx + kx - 1;
                const float* p = nullptr;
                if (MODE == 0) {
                    if (ic < 64)       p = in0 + ((size_t)b * 64 + ic) * HWSZ;
                    else if (ic < 128) p = in1 + ((size_t)b * 64 + ic - 64) * HWSZ;
                    else if (ic < 130) p = in2 + ((size_t)b * 2  + ic - 128) * HWSZ;
                } else {
                    p = in0 + ((size_t)b * IC + ic) * HWSZ;
                }
                float v = 0.f;
                if (p && (unsigned)gy < (unsigned)HH && (unsigned)gx < (unsigned)WW)
                    v = p[gy * WW + gx];
                vh[j] = bf16_rn(v);
                vl[j] = bf16_rn(v - bf16_f(vh[j]));
            }
            short8 ph, pl;
            #pragma unroll
            for (int j2 = 0; j2 < 8; ++j2) { ph[j2] = (short)vh[j2]; pl[j2] = (short)vl[j2]; }
            *(short8*)&iHi[spx * LDK + sko * 8] = ph;
            *(short8*)&iLo[spx * LDK + sko * 8] = pl;
        }
        __syncthreads();

        // ---- MFMA: 2 K-halves x 3 split terms ----
        #pragma unroll
        for (int ks = 0; ks < 2; ++ks) {
            const int koff = ks * 16 + lhi * 8;
            const short8 ah = *(const short8*)&wHi[(wm * 32 + l31) * LDK + koff];
            const short8 al = *(const short8*)&wLo[(wm * 32 + l31) * LDK + koff];
            const int ib = (wn * 32 + l31) * LDK + koff;
            const short8 bh = *(const short8*)&iHi[ib];
            const short8 bl = *(const short8*)&iLo[ib];
            acc = __builtin_amdgcn_mfma_f32_32x32x16_bf16(ah, bh, acc, 0, 0, 0);
            acc = __builtin_amdgcn_mfma_f32_32x32x16_bf16(ah, bl, acc, 0, 0, 0);
            acc = __builtin_amdgcn_mfma_f32_32x32x16_bf16(al, bh, acc, 0, 0, 0);
        }
        __syncthreads();
    }

    // ---- epilogue ----
    const int px = wn * 32 + l31;
    #pragma unroll
    for (int r = 0; r < 16; ++r) {
        const int ocl = wm * 32 + (r & 3) + 8 * (r >> 2) + 4 * lhi;
        const int oc  = o0 + ocl;
        float v = acc[r];
        if (MODE == 2) {
            if (oc < 432) {
                v += bias[oc];
                float res;
                if (oc < 288) {
                    const float fl = flow[(((size_t)b * 2 + ((oc & 1) ? 0 : 1)) * HH + y) * WW + px];
                    res = 10.f * tanhf(v) + fl;
                } else {
                    res = 1.f / (1.f + expf(-v));
                }
                outp[(((size_t)b * 432 + oc) * HH + y) * WW + px] = res;
            }
        } else {
            v += bias[oc];
            v = v >= 0.f ? v : 0.1f * v;
            outp[(((size_t)b * 64 + oc) * HH + y) * WW + px] = v;
        }
    }
}

// ---------------------------------------------------------------------------
// MFMA deformable conv. Block = 64 oc x 64 px, 256 threads (4 waves, 2x2).
// K reordered k-major (kidx = k*64 + c): 18 chunks of 32 = {tap k, 8 dg x 4 ch}.
// Per chunk: bilinear-sample 8dg x 64px (fp32) -> bf16 -> LDS [px][40],
// weights split-bf16 -> 2 MFMA per K-16-step.
// ---------------------------------------------------------------------------
__global__ __launch_bounds__(256) void deform_mfma_k(
    const float* __restrict__ xin, const float* __restrict__ offm,
    const ushort* __restrict__ wdh, const ushort* __restrict__ wdl,
    const float* __restrict__ bias, float* __restrict__ outp)
{
    constexpr int LDK = 40;
    __shared__ ushort wH[64 * LDK], wL[64 * LDK];
    __shared__ ushort iH[64 * LDK];

    const int tid = threadIdx.x;
    const int x0  = blockIdx.x * 64;
    const int y   = blockIdx.y;
    const int b   = blockIdx.z;
    const float* offb = offm + (size_t)b * 432 * HWSZ;
    const float* xb   = xin  + (size_t)b * 64  * HWSZ;

    const int wave = tid >> 6, lane = tid & 63;
    const int wm = wave >> 1, wn = wave & 1;
    const int l31 = lane & 31, lhi = lane >> 5;

    f32x16 acc = {};

    for (int k9 = 0; k9 < 9; ++k9) {
        const float kyf = (float)(k9 / 3 - 1);
        const float kxf = (float)(k9 % 3 - 1);
        #pragma unroll
        for (int half = 0; half < 2; ++half) {
            // ---- stage weights: 64 oc x 32 c ----
            {
                const int woc = tid >> 2, wq = tid & 3;
                const size_t g = (size_t)woc * 576 + k9 * 64 + half * 32 + wq * 8;
                *(short8*)&wH[woc * LDK + wq * 8] = *(const short8*)&wdh[g];
                *(short8*)&wL[woc * LDK + wq * 8] = *(const short8*)&wdl[g];
            }
            // ---- sample 8 dg x 64 px (2 points per thread) ----
            #pragma unroll
            for (int pt = 0; pt < 2; ++pt) {
                const int s   = tid + pt * 256;
                const int pxl = s & 63;
                const int dgl = s >> 6;            // 0..7 (wave-uniform)
                const int dg  = half * 8 + dgl;
                const int xp  = x0 + pxl;
                const int pix = y * WW + xp;
                const float dy = offb[(size_t)(dg * 18 + k9 * 2)     * HWSZ + pix];
                const float dx = offb[(size_t)(dg * 18 + k9 * 2 + 1) * HWSZ + pix];
                const float mk = offb[(size_t)(288 + dg * 9 + k9)    * HWSZ + pix];
                const float py = dy + kyf + (float)y;
                const float px = dx + kxf + (float)xp;
                const float y0f = floorf(py), x0f = floorf(px);
                const float ly = py - y0f, lx = px - x0f;
                const int yi = (int)y0f, xi = (int)x0f;
                const float w00 = (1.f - ly) * (1.f - lx), w01 = (1.f - ly) * lx;
                const float w10 = ly * (1.f - lx),         w11 = ly * lx;
                const bool vy0 = (unsigned)yi < (unsigned)HH, vy1 = (unsigned)(yi + 1) < (unsigned)HH;
                const bool vx0 = (unsigned)xi < (unsigned)WW, vx1 = (unsigned)(xi + 1) < (unsigned)WW;
                const float f00 = (vy0 && vx0) ? w00 * mk : 0.f;
                const float f01 = (vy0 && vx1) ? w01 * mk : 0.f;
                const float f10 = (vy1 && vx0) ? w10 * mk : 0.f;
                const float f11 = (vy1 && vx1) ? w11 * mk : 0.f;
                const int cy0 = min(max(yi, 0), HH - 1), cy1 = min(max(yi + 1, 0), HH - 1);
                const int cx0 = min(max(xi, 0), WW - 1), cx1 = min(max(xi + 1, 0), WW - 1);
                const int i00 = cy0 * WW + cx0, i01 = cy0 * WW + cx1;
                const int i10 = cy1 * WW + cx0, i11 = cy1 * WW + cx1;
                const float* xc = xb + (size_t)(dg * 4) * HWSZ;
                sh4 pk;
                #pragma unroll
                for (int cc = 0; cc < 4; ++cc) {
                    const float v = f00 * xc[i00] + f01 * xc[i01]
                                  + f10 * xc[i10] + f11 * xc[i11];
                    pk[cc] = (short)bf16_rn(v);
                    xc += HWSZ;
                }
                *(sh4*)&iH[pxl * LDK + dgl * 4] = pk;
            }
            __syncthreads();
            // ---- MFMA: 2 K-steps x 2 split terms ----
            #pragma unroll
            for (int ks = 0; ks < 2; ++ks) {
                const int koff = ks * 16 + lhi * 8;
                const short8 ah = *(const short8*)&wH[(wm * 32 + l31) * LDK + koff];
                const short8 al = *(const short8*)&wL[(wm * 32 + l31) * LDK + koff];
                const short8 bb = *(const short8*)&iH[(wn * 32 + l31) * LDK + koff];
                acc = __builtin_amdgcn_mfma_f32_32x32x16_bf16(ah, bb, acc, 0, 0, 0);
                acc = __builtin_amdgcn_mfma_f32_32x32x16_bf16(al, bb, acc, 0, 0, 0);
            }
            __syncthreads();
        }
    }

    // ---- epilogue ----
    const int px = x0 + wn * 32 + l31;
    #pragma unroll
    for (int r = 0; r < 16; ++r) {
        const int oc = wm * 32 + (r & 3) + 8 * (r >> 2) + 4 * lhi;
        outp[(((size_t)b * 64 + oc) * HH + y) * WW + px] = acc[r] + bias[oc];
    }
}

// ---------------------------------------------------------------------------
extern "C" void kernel_launch(void* const* d_in, const int* in_sizes, int n_in,
                              void* d_out, int out_size, void* d_ws, size_t ws_size,
                              hipStream_t stream) {
    const float* x    = (const float*)d_in[0];
    const float* xfw  = (const float*)d_in[1];
    const float* xcur = (const float*)d_in[2];
    const float* flow = (const float*)d_in[3];
    const float* w0   = (const float*)d_in[4];
    const float* b0   = (const float*)d_in[5];
    const float* w1   = (const float*)d_in[6];
    const float* b1   = (const float*)d_in[7];
    const float* w2   = (const float*)d_in[8];
    const float* b2   = (const float*)d_in[9];
    const float* w3   = (const float*)d_in[10];
    const float* b3   = (const float*)d_in[11];
    const float* wdcn = (const float*)d_in[12];
    const float* bdcn = (const float*)d_in[13];
    float* out = (float*)d_out;
    float* ws  = (float*)d_ws;

    // workspace layout (floats)
    float* h0   = ws;                              // 4*64*16384
    float* h1   = h0 + (size_t)BB * CC * HWSZ;     // 4*64*16384
    float* offm = h1 + (size_t)BB * CC * HWSZ;     // 4*432*16384
    ushort* wp  = (ushort*)(offm + (size_t)BB * 432 * HWSZ);
    ushort* wdh  = wp;                 ushort* wdl  = wdh + 64 * 576;
    ushort* w0hi = wdl + 64 * 576;     ushort* w0lo = w0hi + 64 * 1184;
    ushort* w1hi = w0lo + 64 * 1184;   ushort* w1lo = w1hi + 64 * 576;
    ushort* w2hi = w1lo + 64 * 576;    ushort* w2lo = w2hi + 64 * 576;
    ushort* w3hi = w2lo + 64 * 576;    ushort* w3lo = w3hi + 448 * 576;
    // conv2 output reuses h0 (h0 is dead after conv1 reads it)
    float* h2 = h0;

    prep_w_k<<<dim3((64 * 1184 + 255) / 256), dim3(256), 0, stream>>>(w0, w0hi, w0lo, 64, 1170, 64, 1184);
    prep_w_k<<<dim3((64 * 576 + 255) / 256),  dim3(256), 0, stream>>>(w1, w1hi, w1lo, 64, 576, 64, 576);
    prep_w_k<<<dim3((64 * 576 + 255) / 256),  dim3(256), 0, stream>>>(w2, w2hi, w2lo, 64, 576, 64, 576);
    prep_w_k<<<dim3((448 * 576 + 255) / 256), dim3(256), 0, stream>>>(w3, w3hi, w3lo, 432, 576, 448, 576);
    prep_wd_k<<<dim3((64 * 576 + 255) / 256), dim3(256), 0, stream>>>(wdcn, wdh, wdl);

    mfma_conv_k<0, 130, 1184><<<dim3(BB * HH, 1), dim3(512), 0, stream>>>(xfw, xcur, flow, w0hi, w0lo, b0, h0, nullptr);
    mfma_conv_k<1, 64, 576><<<dim3(BB * HH, 1), dim3(512), 0, stream>>>(h0, nullptr, nullptr, w1hi, w1lo, b1, h1, nullptr);
    mfma_conv_k<1, 64, 576><<<dim3(BB * HH, 1), dim3(512), 0, stream>>>(h1, nullptr, nullptr, w2hi, w2lo, b2, h2, nullptr);
    mfma_conv_k<2, 64, 576><<<dim3(BB * HH, 7), dim3(512), 0, stream>>>(h2, nullptr, nullptr, w3hi, w3lo, b3, offm, flow);

    deform_mfma_k<<<dim3(2, 128, BB), dim3(256), 0, stream>>>(x, offm, wdh, wdl, bdcn, out);
}

// Round 4
// 487.934 us; speedup vs baseline: 6.2350x; 1.5805x over previous
//
#include <hip/hip_runtime.h>
#include <hip/hip_bf16.h>
#include <cmath>

#define HH 128
#define WW 128
#define HWSZ (HH*WW)
#define BB 4

typedef __attribute__((ext_vector_type(8))) short short8;
typedef __attribute__((ext_vector_type(4))) short sh4;
typedef __attribute__((ext_vector_type(16))) float f32x16;

__device__ __forceinline__ ushort bf16_rn(float f) {
    uint u = __builtin_bit_cast(uint, f);
    return (ushort)((u + 0x7fffu + ((u >> 16) & 1u)) >> 16);
}
__device__ __forceinline__ float bf16_f(ushort h) {
    uint u = ((uint)h) << 16;
    return __builtin_bit_cast(float, u);
}
__device__ __forceinline__ uint pack_bf(float v) {
    ushort h = bf16_rn(v);
    ushort l = bf16_rn(v - bf16_f(h));
    return ((uint)h << 16) | (uint)l;
}

// ---------------------------------------------------------------------------
// Weight prep: w fp32 [OC][K] -> whi/wlo bf16 [OCpad][KPAD], zero padded.
// ---------------------------------------------------------------------------
__global__ __launch_bounds__(256) void prep_w_k(const float* __restrict__ w,
                                                ushort* __restrict__ whi,
                                                ushort* __restrict__ wlo,
                                                int OC, int K, int OCpad, int KPAD) {
    int idx = blockIdx.x * 256 + threadIdx.x;
    if (idx >= OCpad * KPAD) return;
    int oc = idx / KPAD, k = idx - oc * KPAD;
    float v = (oc < OC && k < K) ? w[(size_t)oc * K + k] : 0.f;
    ushort h = bf16_rn(v);
    ushort l = bf16_rn(v - bf16_f(h));
    whi[idx] = h;
    wlo[idx] = l;
}

// ---------------------------------------------------------------------------
// Deform weight prep: wdcn [oc][c][k] -> k-major reorder [oc][kidx=k*64+c].
// ---------------------------------------------------------------------------
__global__ __launch_bounds__(256) void prep_wd_k(const float* __restrict__ w,
                                                 ushort* __restrict__ whi,
                                                 ushort* __restrict__ wlo) {
    int idx = blockIdx.x * 256 + threadIdx.x;
    if (idx >= 64 * 576) return;
    int oc = idx / 576, kidx = idx - oc * 576;
    int k = kidx >> 6, c = kidx & 63;
    float v = w[(size_t)oc * 576 + c * 9 + k];
    ushort h = bf16_rn(v);
    ushort l = bf16_rn(v - bf16_f(h));
    whi[idx] = h;
    wlo[idx] = l;
}

// ---------------------------------------------------------------------------
// Input concat+pack: {xfw(64), xcur(64), flow(2), zero(2)} -> packed uint
// planes [b][132][H][W] (hi bf16 <<16 | lo bf16).
// ---------------------------------------------------------------------------
__global__ __launch_bounds__(256) void cvt_in_k(const float* __restrict__ xfw,
                                                const float* __restrict__ xcur,
                                                const float* __restrict__ flow,
                                                uint* __restrict__ concatP) {
    int idx = blockIdx.x * 256 + threadIdx.x;
    if (idx >= BB * 132 * HWSZ) return;
    int b = idx / (132 * HWSZ);
    int rem = idx - b * 132 * HWSZ;
    int c = rem / HWSZ, pix = rem - c * HWSZ;
    float v = 0.f;
    if (c < 64)       v = xfw [((size_t)b * 64 + c)       * HWSZ + pix];
    else if (c < 128) v = xcur[((size_t)b * 64 + c - 64)  * HWSZ + pix];
    else if (c < 130) v = flow[((size_t)b * 2  + c - 128) * HWSZ + pix];
    concatP[idx] = pack_bf(v);
}

// ---------------------------------------------------------------------------
// Pack x into gather-friendly float4: xP[b][dg][pix] = x[b][dg*4 .. dg*4+3][pix]
// ---------------------------------------------------------------------------
__global__ __launch_bounds__(256) void pack_x_k(const float* __restrict__ x,
                                                float4* __restrict__ xP) {
    int idx = blockIdx.x * 256 + threadIdx.x;
    if (idx >= BB * 16 * HWSZ) return;
    int b = idx / (16 * HWSZ);
    int rem = idx - b * 16 * HWSZ;
    int dg = rem / HWSZ, pix = rem - dg * HWSZ;
    const float* src = x + ((size_t)b * 64 + dg * 4) * HWSZ + pix;
    float4 v;
    v.x = src[0];
    v.y = src[HWSZ];
    v.z = src[2 * HWSZ];
    v.w = src[3 * HWSZ];
    xP[idx] = v;
}

// ---------------------------------------------------------------------------
// Implicit-GEMM MFMA conv3x3, split-bf16x2 accuracy, packed-uint activations.
// Block: NG*64 oc x 128 px (one image row), 512 threads = 8 waves (2M x 4N).
// k-decode is wave-uniform (readfirstlane) -> SALU. Staging: 1 dword + unpack.
// MODE 1: lrelu, packed-uint output.   MODE 2: conv3 epilogue, fp32 output.
// ---------------------------------------------------------------------------
template<int NG, int IC, int KPAD, int MODE>
__global__ __launch_bounds__(512, 4) void mfma_conv_k(
    const uint* __restrict__ inP,
    const ushort* __restrict__ whi, const ushort* __restrict__ wlo,
    const float* __restrict__ bias, void* __restrict__ outPtr,
    const float* __restrict__ flow, int ngtot)
{
    constexpr int NCHUNK = KPAD / 32;
    constexpr int LDK = 40;

    __shared__ ushort wHi[NG * 64 * LDK], wLo[NG * 64 * LDK];
    __shared__ ushort iHi[128 * LDK], iLo[128 * LDK];

    const int tid = threadIdx.x;
    const int row = blockIdx.x;
    const int b = row >> 7, y = row & 127;
    const int o0 = blockIdx.y * (NG * 64);
    const int ngr = ngtot - (int)blockIdx.y * NG;
    const int ng = ngr < NG ? ngr : NG;

    const int wave = tid >> 6, lane = tid & 63;
    const int wm = wave >> 2, wn = wave & 3;
    const int l31 = lane & 31, lhi = lane >> 5;
    const int spx = tid & 127;
    const int sko = __builtin_amdgcn_readfirstlane(tid >> 7);   // wave-uniform

    f32x16 acc[NG] = {};

    for (int kc = 0; kc < NCHUNK; ++kc) {
        // ---- stage weights: ng*64 oc x 32 k ----
        for (int g4 = tid; g4 < ng * 256; g4 += 512) {
            const int r = g4 >> 2, wq = g4 & 3;
            const size_t gi = (size_t)(o0 + r) * KPAD + kc * 32 + wq * 8;
            *(short8*)&wHi[r * LDK + wq * 8] = *(const short8*)&whi[gi];
            *(short8*)&wLo[r * LDK + wq * 8] = *(const short8*)&wlo[gi];
        }
        // ---- stage im2col: 32 k x 128 px (packed loads, scalar decode) ----
        {
            short8 p8h, p8l;
            #pragma unroll
            for (int j = 0; j < 8; ++j) {
                const int k  = kc * 32 + sko * 8 + j;        // scalar
                const int ic = k / 9;                        // scalar
                const int kk = k - ic * 9;
                const int ky = kk / 3;
                const int kx = kk - ky * 3;
                const int gy = y + ky - 1;                   // scalar
                const uint* prow = inP + ((size_t)b * IC + ic) * HWSZ + gy * WW;
                const int gx = spx + kx - 1;                 // vector
                uint u = 0;
                if ((unsigned)gy < (unsigned)HH && (unsigned)gx < (unsigned)WW)
                    u = prow[gx];
                p8h[j] = (short)(u >> 16);
                p8l[j] = (short)(u & 0xffffu);
            }
            *(short8*)&iHi[spx * LDK + sko * 8] = p8h;
            *(short8*)&iLo[spx * LDK + sko * 8] = p8l;
        }
        __syncthreads();

        // ---- MFMA: 2 K-steps x ng groups x 3 split terms ----
        #pragma unroll
        for (int ks = 0; ks < 2; ++ks) {
            const int koff = ks * 16 + lhi * 8;
            const int ib = (wn * 32 + l31) * LDK + koff;
            const short8 bh = *(const short8*)&iHi[ib];
            const short8 bl = *(const short8*)&iLo[ib];
            #pragma unroll
            for (int g = 0; g < NG; ++g) {
                if (g < ng) {
                    const int ia = (g * 64 + wm * 32 + l31) * LDK + koff;
                    const short8 ah = *(const short8*)&wHi[ia];
                    const short8 al = *(const short8*)&wLo[ia];
                    acc[g] = __builtin_amdgcn_mfma_f32_32x32x16_bf16(ah, bh, acc[g], 0, 0, 0);
                    acc[g] = __builtin_amdgcn_mfma_f32_32x32x16_bf16(ah, bl, acc[g], 0, 0, 0);
                    acc[g] = __builtin_amdgcn_mfma_f32_32x32x16_bf16(al, bh, acc[g], 0, 0, 0);
                }
            }
        }
        __syncthreads();
    }

    // ---- epilogue ----
    const int px = wn * 32 + l31;
    if (MODE == 1) {
        uint* outP = (uint*)outPtr;
        #pragma unroll
        for (int r = 0; r < 16; ++r) {
            const int oc = wm * 32 + (r & 3) + 8 * (r >> 2) + 4 * lhi;
            float v = acc[0][r] + bias[oc];
            v = v >= 0.f ? v : 0.1f * v;
            outP[((size_t)b * 64 + oc) * HWSZ + y * WW + px] = pack_bf(v);
        }
    } else {
        float* outF = (float*)outPtr;
        #pragma unroll
        for (int g = 0; g < NG; ++g) {
            if (g >= ng) break;
            #pragma unroll
            for (int r = 0; r < 16; ++r) {
                const int oc = o0 + g * 64 + wm * 32 + (r & 3) + 8 * (r >> 2) + 4 * lhi;
                if (oc < 432) {
                    float v = acc[g][r] + bias[oc];
                    float res;
                    if (oc < 288) {
                        const float fl = flow[(((size_t)b * 2 + ((oc & 1) ? 0 : 1)) * HH + y) * WW + px];
                        res = 10.f * tanhf(v) + fl;
                    } else {
                        res = 1.f / (1.f + expf(-v));
                    }
                    outF[((size_t)b * 432 + oc) * HWSZ + y * WW + px] = res;
                }
            }
        }
    }
}

// ---------------------------------------------------------------------------
// MFMA deformable conv. Block = 64 oc x 64 px, 256 threads (4 waves, 2x2).
// K k-major (kidx = k*64 + c). Gathers via packed float4 x (4 ch per load).
// ---------------------------------------------------------------------------
__global__ __launch_bounds__(256) void deform_mfma_k(
    const float4* __restrict__ xP, const float* __restrict__ offm,
    const ushort* __restrict__ wdh, const ushort* __restrict__ wdl,
    const float* __restrict__ bias, float* __restrict__ outp)
{
    constexpr int LDK = 40;
    __shared__ ushort wH[64 * LDK], wL[64 * LDK];
    __shared__ ushort iH[64 * LDK];

    const int tid = threadIdx.x;
    const int x0  = blockIdx.x * 64;
    const int y   = blockIdx.y;
    const int b   = blockIdx.z;
    const float* offb = offm + (size_t)b * 432 * HWSZ;

    const int wave = tid >> 6, lane = tid & 63;
    const int wm = wave >> 1, wn = wave & 1;
    const int l31 = lane & 31, lhi = lane >> 5;

    f32x16 acc = {};

    for (int k9 = 0; k9 < 9; ++k9) {
        const float kyf = (float)(k9 / 3 - 1);
        const float kxf = (float)(k9 % 3 - 1);
        #pragma unroll
        for (int half = 0; half < 2; ++half) {
            // ---- stage weights: 64 oc x 32 c ----
            {
                const int woc = tid >> 2, wq = tid & 3;
                const size_t g = (size_t)woc * 576 + k9 * 64 + half * 32 + wq * 8;
                *(short8*)&wH[woc * LDK + wq * 8] = *(const short8*)&wdh[g];
                *(short8*)&wL[woc * LDK + wq * 8] = *(const short8*)&wdl[g];
            }
            // ---- sample 8 dg x 64 px (2 points per thread) ----
            #pragma unroll
            for (int pt = 0; pt < 2; ++pt) {
                const int s   = tid + pt * 256;
                const int pxl = s & 63;
                const int dgl = s >> 6;            // 0..7
                const int dg  = half * 8 + dgl;
                const int xp  = x0 + pxl;
                const int pix = y * WW + xp;
                const float dy = offb[(size_t)(dg * 18 + k9 * 2)     * HWSZ + pix];
                const float dx = offb[(size_t)(dg * 18 + k9 * 2 + 1) * HWSZ + pix];
                const float mk = offb[(size_t)(288 + dg * 9 + k9)    * HWSZ + pix];
                const float py = dy + kyf + (float)y;
                const float px = dx + kxf + (float)xp;
                const float y0f = floorf(py), x0f = floorf(px);
                const float ly = py - y0f, lx = px - x0f;
                const int yi = (int)y0f, xi = (int)x0f;
                const float w00 = (1.f - ly) * (1.f - lx), w01 = (1.f - ly) * lx;
                const float w10 = ly * (1.f - lx),         w11 = ly * lx;
                const bool vy0 = (unsigned)yi < (unsigned)HH, vy1 = (unsigned)(yi + 1) < (unsigned)HH;
                const bool vx0 = (unsigned)xi < (unsigned)WW, vx1 = (unsigned)(xi + 1) < (unsigned)WW;
                const float f00 = (vy0 && vx0) ? w00 * mk : 0.f;
                const float f01 = (vy0 && vx1) ? w01 * mk : 0.f;
                const float f10 = (vy1 && vx0) ? w10 * mk : 0.f;
                const float f11 = (vy1 && vx1) ? w11 * mk : 0.f;
                const int cy0 = min(max(yi, 0), HH - 1), cy1 = min(max(yi + 1, 0), HH - 1);
                const int cx0 = min(max(xi, 0), WW - 1), cx1 = min(max(xi + 1, 0), WW - 1);
                const int i00 = cy0 * WW + cx0, i01 = cy0 * WW + cx1;
                const int i10 = cy1 * WW + cx0, i11 = cy1 * WW + cx1;
                const float4* xg = xP + (size_t)(b * 16 + dg) * HWSZ;
                const float4 c00 = xg[i00], c01 = xg[i01], c10 = xg[i10], c11 = xg[i11];
                sh4 pk;
                pk[0] = (short)bf16_rn(f00 * c00.x + f01 * c01.x + f10 * c10.x + f11 * c11.x);
                pk[1] = (short)bf16_rn(f00 * c00.y + f01 * c01.y + f10 * c10.y + f11 * c11.y);
                pk[2] = (short)bf16_rn(f00 * c00.z + f01 * c01.z + f10 * c10.z + f11 * c11.z);
                pk[3] = (short)bf16_rn(f00 * c00.w + f01 * c01.w + f10 * c10.w + f11 * c11.w);
                *(sh4*)&iH[pxl * LDK + dgl * 4] = pk;
            }
            __syncthreads();
            // ---- MFMA: 2 K-steps x 2 split terms ----
            #pragma unroll
            for (int ks = 0; ks < 2; ++ks) {
                const int koff = ks * 16 + lhi * 8;
                const short8 ah = *(const short8*)&wH[(wm * 32 + l31) * LDK + koff];
                const short8 al = *(const short8*)&wL[(wm * 32 + l31) * LDK + koff];
                const short8 bb = *(const short8*)&iH[(wn * 32 + l31) * LDK + koff];
                acc = __builtin_amdgcn_mfma_f32_32x32x16_bf16(ah, bb, acc, 0, 0, 0);
                acc = __builtin_amdgcn_mfma_f32_32x32x16_bf16(al, bb, acc, 0, 0, 0);
            }
            __syncthreads();
        }
    }

    // ---- epilogue ----
    const int px = x0 + wn * 32 + l31;
    #pragma unroll
    for (int r = 0; r < 16; ++r) {
        const int oc = wm * 32 + (r & 3) + 8 * (r >> 2) + 4 * lhi;
        outp[(((size_t)b * 64 + oc) * HH + y) * WW + px] = acc[r] + bias[oc];
    }
}

// ---------------------------------------------------------------------------
extern "C" void kernel_launch(void* const* d_in, const int* in_sizes, int n_in,
                              void* d_out, int out_size, void* d_ws, size_t ws_size,
                              hipStream_t stream) {
    const float* x    = (const float*)d_in[0];
    const float* xfw  = (const float*)d_in[1];
    const float* xcur = (const float*)d_in[2];
    const float* flow = (const float*)d_in[3];
    const float* w0   = (const float*)d_in[4];
    const float* b0   = (const float*)d_in[5];
    const float* w1   = (const float*)d_in[6];
    const float* b1   = (const float*)d_in[7];
    const float* w2   = (const float*)d_in[8];
    const float* b2   = (const float*)d_in[9];
    const float* w3   = (const float*)d_in[10];
    const float* b3   = (const float*)d_in[11];
    const float* wdcn = (const float*)d_in[12];
    const float* bdcn = (const float*)d_in[13];
    float* out = (float*)d_out;

    // workspace layout (aliased; launch order makes it safe):
    //   [0, 113.2MB)   offm fp32  (concatP aliases its head, dead before conv3)
    //   [+113.2MB)     h0P packed (16.8 MB)   (conv2 output reuses = h2P)
    //   [+16.8MB)      h1P packed (16.8 MB)   (xP aliases after conv2)
    //   [+16.8MB)      weight buffers
    float* offm   = (float*)d_ws;
    uint* concatP = (uint*)d_ws;
    uint* h0P     = (uint*)((char*)d_ws + (size_t)BB * 432 * HWSZ * 4);
    uint* h1P     = h0P + (size_t)BB * 64 * HWSZ;
    float4* xP    = (float4*)h1P;
    ushort* wp    = (ushort*)(h1P + (size_t)BB * 64 * HWSZ);
    ushort* wdh  = wp;                 ushort* wdl  = wdh + 64 * 576;
    ushort* w0hi = wdl + 64 * 576;     ushort* w0lo = w0hi + 64 * 1184;
    ushort* w1hi = w0lo + 64 * 1184;   ushort* w1lo = w1hi + 64 * 576;
    ushort* w2hi = w1lo + 64 * 576;    ushort* w2lo = w2hi + 64 * 576;
    ushort* w3hi = w2lo + 64 * 576;    ushort* w3lo = w3hi + 448 * 576;
    uint* h2P = h0P;   // conv2 output reuses h0P

    prep_w_k<<<dim3((64 * 1184 + 255) / 256), dim3(256), 0, stream>>>(w0, w0hi, w0lo, 64, 1170, 64, 1184);
    prep_w_k<<<dim3((64 * 576 + 255) / 256),  dim3(256), 0, stream>>>(w1, w1hi, w1lo, 64, 576, 64, 576);
    prep_w_k<<<dim3((64 * 576 + 255) / 256),  dim3(256), 0, stream>>>(w2, w2hi, w2lo, 64, 576, 64, 576);
    prep_w_k<<<dim3((448 * 576 + 255) / 256), dim3(256), 0, stream>>>(w3, w3hi, w3lo, 432, 576, 448, 576);
    prep_wd_k<<<dim3((64 * 576 + 255) / 256), dim3(256), 0, stream>>>(wdcn, wdh, wdl);
    cvt_in_k<<<dim3((BB * 132 * HWSZ + 255) / 256), dim3(256), 0, stream>>>(xfw, xcur, flow, concatP);

    mfma_conv_k<1, 132, 1184, 1><<<dim3(BB * HH, 1), dim3(512), 0, stream>>>(concatP, w0hi, w0lo, b0, h0P, nullptr, 1);
    mfma_conv_k<1, 64, 576, 1><<<dim3(BB * HH, 1), dim3(512), 0, stream>>>(h0P, w1hi, w1lo, b1, h1P, nullptr, 1);
    mfma_conv_k<1, 64, 576, 1><<<dim3(BB * HH, 1), dim3(512), 0, stream>>>(h1P, w2hi, w2lo, b2, h2P, nullptr, 1);
    pack_x_k<<<dim3((BB * 16 * HWSZ + 255) / 256), dim3(256), 0, stream>>>(x, xP);
    mfma_conv_k<4, 64, 576, 2><<<dim3(BB * HH, 2), dim3(512), 0, stream>>>(h2P, w3hi, w3lo, b3, offm, flow, 7);

    deform_mfma_k<<<dim3(2, 128, BB), dim3(256), 0, stream>>>(xP, offm, wdh, wdl, bdcn, out);
}